// Round 1
// 331.986 us; speedup vs baseline: 1.0343x; 1.0343x over previous
//
#include <hip/hip_runtime.h>
#include <math.h>
#include <stdint.h>

#define VOCAB 50257
#define KD 5
#define NBATCH 256
#define NT 1024
#define NW (NT / 64)
#define TILE 1024
#define NTILES ((VOCAB + TILE - 1) / TILE) /* 50 */

// One block per batch element. Lazy accept scan (E[rows] ~= 1.0 for these
// inputs), then f64 fallback-sampling over the rejected row.
// vs previous version: float4 phase-3 pass, ballot instead of LDS atomicMin,
// 2-sync phase-1 reduce with thread-0 prefetch, wave-parallel phase 4.
__global__ __launch_bounds__(NT) void spec_decode_kernel(
    const int* __restrict__ dtok,     // [B,K] int32
    const float* __restrict__ dlp,    // [B,K] f32
    const float* __restrict__ logits, // [B,K,V] f32
    const float* __restrict__ rnd,    // [B,K] f32
    const float* __restrict__ usmp,   // [B] f32
    int* __restrict__ out)            // [B*K + B + B] int32
{
    const int b    = blockIdx.x;
    const int tid  = threadIdx.x;
    const int lane = tid & 63;
    const int wv   = tid >> 6;

    __shared__ double s_w[NW];
    __shared__ double s_tileA[NTILES];
    __shared__ double s_tileR[NTILES];
    __shared__ double s_dbc[2];
    __shared__ int    s_ibc[2];
    __shared__ int    s_c[NW];

    // ---------------- Phase 1: lazy accept/reject scan ----------------
    double Zsel  = 0.0; // Z of the last row processed (== rejected row when n_acc < K)
    int    n_acc = KD;
    for (int r = 0; r < KD; ++r) {
        const float* row = logits + ((size_t)b * KD + r) * (size_t)VOCAB;
        // peel to 16B alignment (V odd -> rows are only 4B aligned)
        const int head = (int)((4u - ((((uintptr_t)row) >> 2) & 3u)) & 3u);

        // thread 0 prefetches the scalars it needs after the scan
        float tlogit = 0.f, dl = 0.f, rv = 0.f;
        if (tid == 0) {
            int tok = dtok[b * KD + r];
            tlogit  = row[tok];
            dl      = dlp[b * KD + r];
            rv      = rnd[b * KD + r];
        }

        double l0 = 0.0, l1 = 0.0; // two accumulators (shorter f64 dep chain)
        if (tid < head) l0 += (double)expf(row[tid]);
        const int nvec = (VOCAB - head) >> 2;
        const float4* row4 = (const float4*)(row + head);
        for (int i = tid; i < nvec; i += NT) {
            float4 x = row4[i];
            l0 += (double)expf(x.x) + (double)expf(x.y);
            l1 += (double)expf(x.z) + (double)expf(x.w);
        }
        const int tail_start = head + (nvec << 2);
        const int tail_cnt   = VOCAB - tail_start;
        if (tid < tail_cnt) l1 += (double)expf(row[tail_start + tid]);

        double local = l0 + l1;
        for (int off = 32; off; off >>= 1) local += __shfl_down(local, off, 64);
        if (lane == 0) s_w[wv] = local;
        __syncthreads();
        if (wv == 0) {
            double v = (lane < NW) ? s_w[lane] : 0.0;
            for (int off = 8; off; off >>= 1) v += __shfl_down(v, off, 64);
            if (lane == 0) {
                double Z   = v;
                double tlp = (double)tlogit - log(Z);
                double ap  = exp(tlp - (double)dl);
                if (ap > 1.0) ap = 1.0;
                s_dbc[0] = Z;
                s_ibc[0] = ((double)rv < ap) ? 1 : 0;
            }
        }
        __syncthreads();
        Zsel = s_dbc[0];
        int acc = s_ibc[0];
        // no extra sync needed: s_dbc/s_ibc are rewritten only between the
        // next row's sync pair; s_w[wv] is rewritten only after the next row's
        // full scan, i.e. after every wave passed the sync above.
        if (!acc) { n_acc = r; break; }
    }

    // ---------------- Phase 2: write accepted tokens / n ----------------
    if (tid == 0) {
        for (int r = 0; r < KD; ++r)
            out[b * KD + r] = (r < n_acc) ? dtok[b * KD + r] : 0;
        out[NBATCH * KD + b] = n_acc;
        if (n_acc >= KD) out[NBATCH * KD + NBATCH + b] = 0; // PAD, no resample
    }
    if (n_acc >= KD) return; // block-uniform

    const int    rp   = n_acc; // == min(first_reject, K-1) since n_acc < K
    const float* row  = logits + ((size_t)b * KD + rp) * (size_t)VOCAB;
    const double invZ = 1.0 / Zsel;
    const double dp   = exp((double)dlp[b * KD + rp]);
    const int    head = (int)((4u - ((((uintptr_t)row) >> 2) & 3u)) & 3u);

    // ---------------- Phase 3: tile sums (adjusted + raw), float4 ----------
    // tiles are 4096B-aligned relative to the row pointer, so each tile has
    // the same peel: 'head' scalars, vcnt float4s, then a tail.
    for (int t = wv; t < NTILES; t += NW) {
        const int start = t * TILE;
        int end = start + TILE; if (end > VOCAB) end = VOCAB;
        double aS = 0.0, rS = 0.0;
        if (lane < head) {
            double p = exp((double)row[start + lane]) * invZ;
            rS += p;
            double a = p - dp;
            if (a > 0.0) aS += a;
        }
        const int vcnt = (end - start - head) >> 2;
        const float4* v4 = (const float4*)(row + start + head);
        for (int j = lane; j < vcnt; j += 64) {
            float4 x = v4[j];
            double p0 = exp((double)x.x) * invZ;
            double p1 = exp((double)x.y) * invZ;
            double p2 = exp((double)x.z) * invZ;
            double p3 = exp((double)x.w) * invZ;
            rS += p0 + p1 + p2 + p3;
            double a0 = p0 - dp; if (a0 > 0.0) aS += a0;
            double a1 = p1 - dp; if (a1 > 0.0) aS += a1;
            double a2 = p2 - dp; if (a2 > 0.0) aS += a2;
            double a3 = p3 - dp; if (a3 > 0.0) aS += a3;
        }
        const int ts = start + head + (vcnt << 2);
        if (lane < end - ts) {
            double p = exp((double)row[ts + lane]) * invZ;
            rS += p;
            double a = p - dp;
            if (a > 0.0) aS += a;
        }
        for (int off = 32; off; off >>= 1) {
            aS += __shfl_down(aS, off, 64);
            rS += __shfl_down(rS, off, 64);
        }
        if (lane == 0) { s_tileA[t] = aS; s_tileR[t] = rS; }
    }
    __syncthreads();

    // ---------------- Phase 4: pick crossing tile (wave 0, parallel) -------
    if (wv == 0) {
        double a  = (lane < NTILES) ? s_tileA[lane] : 0.0;
        double rr = (lane < NTILES) ? s_tileR[lane] : 0.0;
        double sa = a, sr = rr; // inclusive scans over tile index == lane
        for (int off = 1; off < 64; off <<= 1) {
            double va = __shfl_up(sa, (unsigned)off, 64); if (lane >= off) sa += va;
            double vr = __shfl_up(sr, (unsigned)off, 64); if (lane >= off) sr += vr;
        }
        double S      = __shfl(sa, NTILES - 1, 64); // total adjusted mass
        int    useAdj = (S > 0.0) ? 1 : 0;
        double Tot    = useAdj ? S : __shfl(sr, NTILES - 1, 64);
        double T      = (double)usmp[b] * Tot;
        double incl   = useAdj ? sa : sr;
        double tval   = useAdj ? a : rr;
        bool crossed  = (lane < NTILES) && (incl >= T);
        unsigned long long mk = __ballot(crossed);
        int ct = mk ? (int)(__ffsll(mk) - 1) : (NTILES - 1);
        double P = __shfl(incl, ct, 64) - __shfl(tval, ct, 64); // exclusive prefix
        if (lane == 0) {
            s_dbc[0] = P;
            s_dbc[1] = T;
            s_ibc[0] = ct;
            s_ibc[1] = useAdj;
        }
    }
    __syncthreads();

    // ---------------- Phase 5: in-tile ordered scan -> sampled index ------
    {
        double Pb     = s_dbc[0];
        double T      = s_dbc[1];
        int    ct     = s_ibc[0];
        int    useAdj = s_ibc[1];
        int    idx    = ct * TILE + tid;
        double g      = 0.0;
        if (idx < VOCAB) {
            double p = exp((double)row[idx]) * invZ;
            if (useAdj) {
                double a = p - dp;
                g = (a > 0.0) ? a : 0.0;
            } else {
                g = p;
            }
        }
        // wave inclusive scan
        double sc = g;
        for (int off = 1; off < 64; off <<= 1) {
            double v = __shfl_up(sc, (unsigned)off, 64);
            if (lane >= off) sc += v;
        }
        if (lane == 63) s_w[wv] = sc;
        __syncthreads();
        double woff = 0.0;
        for (int w = 0; w < wv; ++w) woff += s_w[w];
        double incl = Pb + woff + sc;
        // crossing set is a suffix in tid order -> first set lane per wave,
        // then min across waves (no serialized LDS atomics)
        bool cross = (idx < VOCAB) && (incl >= T);
        unsigned long long mk = __ballot(cross);
        if (lane == 0)
            s_c[wv] = mk ? (int)(wv * 64 + __ffsll(mk) - 1) : 0x7FFFFFFF;
        __syncthreads();
        if (tid == 0) {
            int best = 0x7FFFFFFF;
            for (int w = 0; w < NW; ++w) best = min(best, s_c[w]);
            int smp;
            if (best == 0x7FFFFFFF) { // rounding guard: fall back to tile end
                smp = ct * TILE + TILE - 1;
                if (smp > VOCAB - 1) smp = VOCAB - 1;
            } else {
                smp = ct * TILE + best;
            }
            out[NBATCH * KD + NBATCH + b] = smp;
        }
    }
}

extern "C" void kernel_launch(void* const* d_in, const int* in_sizes, int n_in,
                              void* d_out, int out_size, void* d_ws, size_t ws_size,
                              hipStream_t stream) {
    const int*   dtok   = (const int*)d_in[0];
    const float* dlp    = (const float*)d_in[1];
    const float* logits = (const float*)d_in[2];
    const float* rnd    = (const float*)d_in[3];
    const float* usmp   = (const float*)d_in[4];
    int*         out    = (int*)d_out;
    (void)in_sizes; (void)n_in; (void)out_size; (void)d_ws; (void)ws_size;
    spec_decode_kernel<<<dim3(NBATCH), dim3(NT), 0, stream>>>(
        dtok, dlp, logits, rnd, usmp, out);
}